// Round 3
// baseline (524.263 us; speedup 1.0000x reference)
//
#include <hip/hip_runtime.h>
#include <hip/hip_bf16.h>

// ---------- types ----------
typedef __attribute__((ext_vector_type(4))) float  f32x4;
typedef __attribute__((ext_vector_type(8))) __bf16 bf16x8;
typedef __attribute__((ext_vector_type(4))) __bf16 bf16x4;

#define B_DIM 128
#define S_DIM 512
#define D_DIM 512
#define H_DIM 512
#define V_DIM 50000

// d_out layout (floats): output[128*50000] | hidden[65536] | cell[65536] | attn[65536]
#define OUT_HID  (B_DIM * V_DIM)
#define OUT_CELL (OUT_HID + B_DIM * H_DIM)
#define OUT_ATTN (OUT_CELL + B_DIM * H_DIM)

__device__ __forceinline__ float fast_tanh(float x) {
    float e = __expf(2.0f * x);
    return 1.0f - 2.0f / (e + 1.0f);
}
__device__ __forceinline__ float fast_sigmoid(float x) {
    return 1.0f / (1.0f + __expf(-x));
}

// ---------- mask staging-mode autodetect ----------
// Scans first 16384 u32 words (=64KB, safe for both stagings of a 65536-elem
// mask). int32-staged 0/1 mask -> every word <=1 -> flag stays 0.
// byte-staged -> words pack 4 random bools -> some word >1 -> flag=1.
__global__ void k_maskdetect(const unsigned int* __restrict__ m, int* __restrict__ flag) {
    int i = blockIdx.x * 256 + threadIdx.x;       // 16384 threads
    unsigned int v = m[i];
    unsigned long long any = __ballot(v > 1u);
    if ((threadIdx.x & 63) == 0 && any) atomicOr(flag, 1);
}

// ---------- pack y_prev | (ctx later) | h0 into A_cat [128][1536] ----------
__global__ void k_pack(const float* __restrict__ y_prev, const float* __restrict__ h0,
                       float* __restrict__ Acat) {
    int g = blockIdx.x * 256 + threadIdx.x;           // 65536
    int b = g >> 9, d = g & 511;
    Acat[b * 1536 + d]        = y_prev[g];
    Acat[b * 1536 + 1024 + d] = h0[g];
}

// ---------- wq = h0 @ W_q^T + b_q  [128][512] ----------
__global__ void k_wq(const float* __restrict__ h0, const float* __restrict__ Wq,
                     const float* __restrict__ bq, float* __restrict__ wq) {
    int g = blockIdx.x * 256 + threadIdx.x;           // 65536
    int b = g >> 9, e = g & 511;
    const f32x4* hv = reinterpret_cast<const f32x4*>(h0 + b * 512);
    const f32x4* wv = reinterpret_cast<const f32x4*>(Wq + e * 512);
    float acc = 0.0f;
    #pragma unroll 8
    for (int k = 0; k < 128; k++) {
        f32x4 a = hv[k], w = wv[k];
        acc += a[0]*w[0] + a[1]*w[1] + a[2]*w[2] + a[3]*w[3];
    }
    wq[g] = acc + bq[e];
}

// ---------- fused scores GEMM: uh = enc·Wc^T ; scores += v·tanh(wq+uh) ----------
// grid (4 n-tiles, 512 m-tiles), 256 threads, tile 128x128, BK=32
__global__ __launch_bounds__(256) void k_scores(
    const float* __restrict__ enc, const float* __restrict__ Wc,
    const float* __restrict__ wq, const float* __restrict__ vw,
    float* __restrict__ scores) {
    __shared__ __bf16 As[128][40];
    __shared__ __bf16 Bs[128][40];
    const int tid = threadIdx.x;
    const int bn = blockIdx.x;     // 0..3
    const int bm = blockIdx.y;     // 0..511
    const int lane = tid & 63, wid = tid >> 6;
    const int wr = wid >> 1, wc = wid & 1;
    const int l15 = lane & 15, lq = lane >> 4;

    f32x4 acc[4][4] = {};

    for (int k0 = 0; k0 < 512; k0 += 32) {
        if (k0) __syncthreads();
        #pragma unroll
        for (int i = 0; i < 4; i++) {
            int lin = tid + i * 256;                 // float4 slot, 1024 total
            int row = lin >> 3;
            int c4  = (lin & 7) << 2;
            f32x4 va = *reinterpret_cast<const f32x4*>(&enc[(bm * 128 + row) * 512 + k0 + c4]);
            f32x4 vb = *reinterpret_cast<const f32x4*>(&Wc [(bn * 128 + row) * 512 + k0 + c4]);
            bf16x4 ba, bb;
            #pragma unroll
            for (int j = 0; j < 4; j++) { ba[j] = (__bf16)va[j]; bb[j] = (__bf16)vb[j]; }
            *reinterpret_cast<bf16x4*>(&As[row][c4]) = ba;
            *reinterpret_cast<bf16x4*>(&Bs[row][c4]) = bb;
        }
        __syncthreads();
        bf16x8 af[4], bfr[4];
        #pragma unroll
        for (int mi = 0; mi < 4; mi++)
            af[mi] = *reinterpret_cast<const bf16x8*>(&As[wr * 64 + mi * 16 + l15][lq * 8]);
        #pragma unroll
        for (int ni = 0; ni < 4; ni++)
            bfr[ni] = *reinterpret_cast<const bf16x8*>(&Bs[wc * 64 + ni * 16 + l15][lq * 8]);
        #pragma unroll
        for (int mi = 0; mi < 4; mi++)
            #pragma unroll
            for (int ni = 0; ni < 4; ni++)
                acc[mi][ni] = __builtin_amdgcn_mfma_f32_16x16x32_bf16(af[mi], bfr[ni], acc[mi][ni], 0, 0, 0);
    }

    // epilogue: val = tanh(acc + wq[b,e]) * v[e]; row-reduce over 16 lanes; atomicAdd
    #pragma unroll
    for (int mi = 0; mi < 4; mi++) {
        int rowBase = bm * 128 + wr * 64 + mi * 16;  // global row = b*S + s (tile stays in one b)
        int b = rowBase >> 9;
        const float* wqr = wq + b * 512;
        float rs0 = 0, rs1 = 0, rs2 = 0, rs3 = 0;
        #pragma unroll
        for (int ni = 0; ni < 4; ni++) {
            int ge = bn * 128 + wc * 64 + ni * 16 + l15;
            float wqv = wqr[ge];
            float vv  = vw[ge];
            rs0 += fast_tanh(acc[mi][ni][0] + wqv) * vv;
            rs1 += fast_tanh(acc[mi][ni][1] + wqv) * vv;
            rs2 += fast_tanh(acc[mi][ni][2] + wqv) * vv;
            rs3 += fast_tanh(acc[mi][ni][3] + wqv) * vv;
        }
        #pragma unroll
        for (int o = 8; o; o >>= 1) {
            rs0 += __shfl_xor(rs0, o, 64);
            rs1 += __shfl_xor(rs1, o, 64);
            rs2 += __shfl_xor(rs2, o, 64);
            rs3 += __shfl_xor(rs3, o, 64);
        }
        if (l15 == 0) {
            int r0 = rowBase + lq * 4;
            atomicAdd(&scores[r0 + 0], rs0);
            atomicAdd(&scores[r0 + 1], rs1);
            atomicAdd(&scores[r0 + 2], rs2);
            atomicAdd(&scores[r0 + 3], rs3);
        }
    }
}

// ---------- masked softmax over S=512 per batch row ----------
// mask interpretation chosen at runtime via detected flag
__global__ __launch_bounds__(256) void k_softmax(const float* __restrict__ scores,
                                                 const void* __restrict__ maskraw,
                                                 const int* __restrict__ flag,
                                                 float* __restrict__ attn) {
    int b = blockIdx.x, t = threadIdx.x;
    const float* sr = scores + b * 512;
    int m0, m1;
    if (*flag) {    // byte-staged bool
        const unsigned char* mr = (const unsigned char*)maskraw + b * 512;
        m0 = mr[t]; m1 = mr[t + 256];
    } else {        // int32-staged
        const int* mr = (const int*)maskraw + b * 512;
        m0 = mr[t]; m1 = mr[t + 256];
    }
    float s0 = sr[t], s1 = sr[t + 256];
    const float NEG = -3.0e38f;
    float mx = fmaxf(m0 ? NEG : s0, m1 ? NEG : s1);
    #pragma unroll
    for (int o = 32; o; o >>= 1) mx = fmaxf(mx, __shfl_xor(mx, o, 64));
    __shared__ float r1[4], r2[4];
    int wid = t >> 6, lane = t & 63;
    if (!lane) r1[wid] = mx;
    __syncthreads();
    mx = fmaxf(fmaxf(r1[0], r1[1]), fmaxf(r1[2], r1[3]));
    float e0 = m0 ? 0.0f : __expf(s0 - mx);
    float e1 = m1 ? 0.0f : __expf(s1 - mx);
    float sm = e0 + e1;
    #pragma unroll
    for (int o = 32; o; o >>= 1) sm += __shfl_xor(sm, o, 64);
    if (!lane) r2[wid] = sm;
    __syncthreads();
    sm = r2[0] + r2[1] + r2[2] + r2[3];
    float inv = 1.0f / sm;
    attn[b * 512 + t]       = e0 * inv;
    attn[b * 512 + 256 + t] = e1 * inv;
}

// ---------- ctx[b,:] = sum_s attn[b,s] * enc[b,s,:]  -> Acat[:,512:1024] ----------
__global__ void k_ctx(const float* __restrict__ enc, const float* __restrict__ attn,
                      float* __restrict__ Acat) {
    int sc = blockIdx.x;          // 8 chunks of 64 s
    int b  = blockIdx.y;
    int t  = threadIdx.x;         // 128 (float4 over D=512)
    __shared__ float aw[64];
    if (t < 64) aw[t] = attn[b * 512 + sc * 64 + t];
    __syncthreads();
    const f32x4* ep = reinterpret_cast<const f32x4*>(enc) + ((size_t)b * 512 + sc * 64) * 128;
    f32x4 acc = {0.0f, 0.0f, 0.0f, 0.0f};
    #pragma unroll 4
    for (int s = 0; s < 64; s++) {
        f32x4 v = ep[s * 128 + t];
        float w = aw[s];
        acc[0] += w * v[0]; acc[1] += w * v[1]; acc[2] += w * v[2]; acc[3] += w * v[3];
    }
    float* dst = &Acat[b * 1536 + 512 + t * 4];
    atomicAdd(dst + 0, acc[0]);
    atomicAdd(dst + 1, acc[1]);
    atomicAdd(dst + 2, acc[2]);
    atomicAdd(dst + 3, acc[3]);
}

// ---------- gates GEMM: G += Acat[128,1536] @ [W_ih | W_hh]^T  [128,2048] ----------
// grid (32 n-tiles, 2 m-tiles, 4 k-chunks), 256 threads, tile 64x64, BK=32, f32
__global__ __launch_bounds__(256) void k_gates(
    const float* __restrict__ Acat, const float* __restrict__ Wih,
    const float* __restrict__ Whh, float* __restrict__ G) {
    __shared__ float AsT[32][68];
    __shared__ float WsT[32][68];
    int tid = threadIdx.x;
    int bn = blockIdx.x, bm = blockIdx.y, kz = blockIdx.z;
    int tm = tid >> 4, tn = tid & 15;
    float acc[4][4] = {};
    int kBeg = kz * 384;
    for (int k0 = kBeg; k0 < kBeg + 384; k0 += 32) {
        if (k0 != kBeg) __syncthreads();
        #pragma unroll
        for (int i = 0; i < 2; i++) {
            int lin = tid + i * 256;                  // 512 float4 slots
            int row = lin >> 3;
            int c4  = (lin & 7) << 2;
            f32x4 va = *reinterpret_cast<const f32x4*>(&Acat[(bm * 64 + row) * 1536 + k0 + c4]);
            int n = bn * 64 + row;
            int k = k0 + c4;
            f32x4 vb = (k < 1024)
                ? *reinterpret_cast<const f32x4*>(&Wih[n * 1024 + k])
                : *reinterpret_cast<const f32x4*>(&Whh[n * 512 + (k - 1024)]);
            #pragma unroll
            for (int j = 0; j < 4; j++) {
                AsT[c4 + j][row] = va[j];
                WsT[c4 + j][row] = vb[j];
            }
        }
        __syncthreads();
        #pragma unroll
        for (int k = 0; k < 32; k++) {
            f32x4 a = *reinterpret_cast<const f32x4*>(&AsT[k][tm * 4]);
            f32x4 w = *reinterpret_cast<const f32x4*>(&WsT[k][tn * 4]);
            #pragma unroll
            for (int i2 = 0; i2 < 4; i2++)
                #pragma unroll
                for (int j2 = 0; j2 < 4; j2++)
                    acc[i2][j2] += a[i2] * w[j2];
        }
    }
    #pragma unroll
    for (int i2 = 0; i2 < 4; i2++) {
        int m = bm * 64 + tm * 4 + i2;
        int n = bn * 64 + tn * 4;
        #pragma unroll
        for (int j2 = 0; j2 < 4; j2++)
            atomicAdd(&G[m * 2048 + n + j2], acc[i2][j2]);
    }
}

// ---------- LSTM pointwise ----------
__global__ void k_lstm(const float* __restrict__ G, const float* __restrict__ bih,
                       const float* __restrict__ bhh, const float* __restrict__ c0,
                       float* __restrict__ hid, float* __restrict__ cell) {
    int g = blockIdx.x * 256 + threadIdx.x;           // 65536
    int b = g >> 9, h = g & 511;
    const float* gr = G + b * 2048;
    float xi = gr[h]          + bih[h]          + bhh[h];
    float xf = gr[512 + h]    + bih[512 + h]    + bhh[512 + h];
    float xg = gr[1024 + h]   + bih[1024 + h]   + bhh[1024 + h];
    float xo = gr[1536 + h]   + bih[1536 + h]   + bhh[1536 + h];
    float ig = fast_sigmoid(xi), fg = fast_sigmoid(xf);
    float gg = fast_tanh(xg),    og = fast_sigmoid(xo);
    float c  = fg * c0[g] + ig * gg;
    float hh = og * fast_tanh(c);
    cell[g] = c;
    hid[g]  = hh;
}

// ---------- output GEMM: out = hidden[128,512] @ ent_W^T[512,50000] + ent_b ----------
// grid 391 n-tiles, tile 128x128, BK=32
__global__ __launch_bounds__(256) void k_out(
    const float* __restrict__ hid, const float* __restrict__ W,
    const float* __restrict__ bias, float* __restrict__ out) {
    __shared__ __bf16 As[128][40];
    __shared__ __bf16 Bs[128][40];
    const int tid = threadIdx.x;
    const int bn = blockIdx.x;     // 0..390
    const int lane = tid & 63, wid = tid >> 6;
    const int wr = wid >> 1, wc = wid & 1;
    const int l15 = lane & 15, lq = lane >> 4;

    f32x4 acc[4][4] = {};

    for (int k0 = 0; k0 < 512; k0 += 32) {
        if (k0) __syncthreads();
        #pragma unroll
        for (int i = 0; i < 4; i++) {
            int lin = tid + i * 256;
            int row = lin >> 3;
            int c4  = (lin & 7) << 2;
            f32x4 va = *reinterpret_cast<const f32x4*>(&hid[row * 512 + k0 + c4]);
            int n = bn * 128 + row;
            f32x4 vb = {0.0f, 0.0f, 0.0f, 0.0f};
            if (n < V_DIM) vb = *reinterpret_cast<const f32x4*>(&W[n * 512 + k0 + c4]);
            bf16x4 ba, bb;
            #pragma unroll
            for (int j = 0; j < 4; j++) { ba[j] = (__bf16)va[j]; bb[j] = (__bf16)vb[j]; }
            *reinterpret_cast<bf16x4*>(&As[row][c4]) = ba;
            *reinterpret_cast<bf16x4*>(&Bs[row][c4]) = bb;
        }
        __syncthreads();
        bf16x8 af[4], bfr[4];
        #pragma unroll
        for (int mi = 0; mi < 4; mi++)
            af[mi] = *reinterpret_cast<const bf16x8*>(&As[wr * 64 + mi * 16 + l15][lq * 8]);
        #pragma unroll
        for (int ni = 0; ni < 4; ni++)
            bfr[ni] = *reinterpret_cast<const bf16x8*>(&Bs[wc * 64 + ni * 16 + l15][lq * 8]);
        #pragma unroll
        for (int mi = 0; mi < 4; mi++)
            #pragma unroll
            for (int ni = 0; ni < 4; ni++)
                acc[mi][ni] = __builtin_amdgcn_mfma_f32_16x16x32_bf16(af[mi], bfr[ni], acc[mi][ni], 0, 0, 0);
    }

    #pragma unroll
    for (int mi = 0; mi < 4; mi++) {
        #pragma unroll
        for (int ni = 0; ni < 4; ni++) {
            int gn = bn * 128 + wc * 64 + ni * 16 + l15;
            if (gn < V_DIM) {
                float bv = bias[gn];
                int gm = wr * 64 + mi * 16 + lq * 4;
                out[(gm + 0) * V_DIM + gn] = acc[mi][ni][0] + bv;
                out[(gm + 1) * V_DIM + gn] = acc[mi][ni][1] + bv;
                out[(gm + 2) * V_DIM + gn] = acc[mi][ni][2] + bv;
                out[(gm + 3) * V_DIM + gn] = acc[mi][ni][3] + bv;
            }
        }
    }
}

extern "C" void kernel_launch(void* const* d_in, const int* in_sizes, int n_in,
                              void* d_out, int out_size, void* d_ws, size_t ws_size,
                              hipStream_t stream) {
    const float* y_prev = (const float*)d_in[0];
    const float* h0     = (const float*)d_in[1];
    const float* c0     = (const float*)d_in[2];
    const float* enc    = (const float*)d_in[3];
    // d_in[4] = src_word_embeds (unused by reference)
    const void* mask = d_in[5];
    const float* Wc   = (const float*)d_in[6];
    const float* Wq   = (const float*)d_in[7];
    const float* bq   = (const float*)d_in[8];
    const float* vw   = (const float*)d_in[9];
    // d_in[10] = v_b (softmax shift-invariant -> no effect on any output)
    const float* Wih  = (const float*)d_in[11];
    const float* Whh  = (const float*)d_in[12];
    const float* bih  = (const float*)d_in[13];
    const float* bhh  = (const float*)d_in[14];
    const float* entW = (const float*)d_in[15];
    const float* entb = (const float*)d_in[16];

    float* ws     = (float*)d_ws;
    float* wq     = ws;                 // 65536
    float* scores = ws + 65536;         // 65536
    float* Acat   = ws + 131072;        // 128*1536 = 196608
    float* G      = ws + 327680;        // 128*2048 = 262144
    int*   mflag  = (int*)(ws + 589824); // 1 int (inside zeroed region)

    float* out  = (float*)d_out;
    float* hid  = out + OUT_HID;
    float* cell = out + OUT_CELL;
    float* attn = out + OUT_ATTN;

    // zero scores + Acat + G + mflag (contiguous region)
    (void)hipMemsetAsync(scores, 0, (size_t)(65536 + 196608 + 262144 + 16) * sizeof(float), stream);

    k_maskdetect<<<64, 256, 0, stream>>>((const unsigned int*)mask, mflag);
    k_pack<<<256, 256, 0, stream>>>(y_prev, h0, Acat);
    k_wq<<<256, 256, 0, stream>>>(h0, Wq, bq, wq);
    k_scores<<<dim3(4, 512), 256, 0, stream>>>(enc, Wc, wq, vw, scores);
    k_softmax<<<128, 256, 0, stream>>>(scores, mask, mflag, attn);
    k_ctx<<<dim3(8, 128), 128, 0, stream>>>(enc, attn, Acat);
    k_gates<<<dim3(32, 2, 4), 256, 0, stream>>>(Acat, Wih, Whh, G);
    k_lstm<<<256, 256, 0, stream>>>(G, bih, bhh, c0, hid, cell);
    k_out<<<391, 256, 0, stream>>>(hid, entW, entb, out);
}